// Round 17
// baseline (105.146 us; speedup 1.0000x reference)
//
#include <hip/hip_runtime.h>
#include <hip/hip_bf16.h>

// DigitCaps, fp32 in / fp32 out:
//   u [16,1152,8], W [10,1152,16,8], Bp [10,1,1152], out [16,10,16]
// Exact algebra: A_sum[b,d,m] = dot(T[b,d,:], U_hat[b,d,m,:])/sqrt8,
//   T = sum_n U_hat;  C = softmax_d;  S = sum_n (Bp+C)*U_hat;  squash(S).
// Measured laws: (r10/13/16) 4 dispatches -> 83us regardless of internals:
// per-dispatch fixed cost ~16-20us dominates. (r14) NEVER spin. (r15) never
// fence after bulk dirty plain stores. (r12) write-through atomicAdd +
// last-arrival ticket is safe & correct. Round 17: TWO dispatches.
//  K1: T partials (plain stores, boundary-published) + zeroes Ssp/cnt.
//  K2: Tp-reduce in LDS, softmax/S math, atomicAdd into 4 splits (only
//      atomics before the fence), ticket; last block squashes + stores out.
constexpr int BN = 16, NN = 1152, DP = 8, ND = 10, DD = 16;
constexpr int CELLS = BN * ND * DD;   // 2560; cell = d*256 + b*16 + j
constexpr int NCH1 = 48;              // n's per K1 block
constexpr int NCHK = NN / NCH1;       // 24 T-partial chunks
constexpr int NBLK1 = NCHK * ND;      // 240 K1 blocks (one d each)
constexpr int NCH2 = 4;               // n's per K2 block
constexpr int NBLK2 = NN / NCH2;      // 288 K2 blocks
constexpr int SPLIT = 4;              // S atomic splits (72 RMW/addr)

// ---- K1: partial T per (d, 48-n chunk); plain coalesced stores ----
__global__ __launch_bounds__(256) void caps_T(
    const float* __restrict__ u, const float* __restrict__ W,
    float* __restrict__ Tp, float* __restrict__ Ssp,
    unsigned* __restrict__ cnt)
{
    __shared__ float Wl[NCH1 * 128];      // 24 KB: W[d, n0..n0+47, :, :]
    __shared__ float ul[BN * NCH1 * DP];  // 24 KB: u[:, n0..n0+47, :]
    const int t = threadIdx.x;
    const int d = blockIdx.x / NCHK, c = blockIdx.x % NCHK;
    const int n0 = c * NCH1;

    for (int g = t; g < NCH1 * 32; g += 256) {      // 6 indep float4 loads
        const int nn = g >> 5, w = g & 31;
        reinterpret_cast<float4*>(Wl)[g] =
            *reinterpret_cast<const float4*>(
                W + ((size_t)d * NN + n0 + nn) * (DD * DP) + w * 4);
    }
    for (int g = t; g < BN * NCH1 * 2; g += 256) {  // 6 indep float4 loads
        const int b = g / (NCH1 * 2), r = g % (NCH1 * 2);
        const int nn = r >> 1, half = r & 1;
        reinterpret_cast<float4*>(ul)[g] =
            *reinterpret_cast<const float4*>(
                u + ((size_t)b * NN + n0 + nn) * DP + half * 4);
    }
    if (blockIdx.x == 0) {   // zero S splits + ticket (published at boundary)
        for (int g = t; g < SPLIT * CELLS / 4; g += 256)
            reinterpret_cast<float4*>(Ssp)[g] = make_float4(0.f, 0.f, 0.f, 0.f);
        if (t == 0) *cnt = 0u;
    }
    __syncthreads();

    const int j = t & 15, b = t >> 4;
    float acc = 0.f;
#pragma unroll
    for (int nn = 0; nn < NCH1; ++nn) {   // u-read broadcasts over 16 j-lanes
        const float4 u0 = reinterpret_cast<const float4*>(ul)[(b * NCH1 + nn) * 2];
        const float4 u1 = reinterpret_cast<const float4*>(ul)[(b * NCH1 + nn) * 2 + 1];
        const float4* wp = reinterpret_cast<const float4*>(Wl) + nn * 32 + j * 2;
        const float4 w0 = wp[0], w1 = wp[1];
        acc += w0.x * u0.x + w0.y * u0.y + w0.z * u0.z + w0.w * u0.w
             + w1.x * u1.x + w1.y * u1.y + w1.z * u1.z + w1.w * u1.w;
    }
    Tp[(size_t)c * CELLS + d * 256 + t] = acc;      // 1 KB coalesced run
}

// ---- K2: Tp-reduce -> softmax_d -> S atomics -> ticket -> squash ----
__global__ __launch_bounds__(256) void caps_S(
    const float* __restrict__ u, const float* __restrict__ W,
    const float* __restrict__ Bp, const float* __restrict__ Tp,
    float* __restrict__ Ssp, unsigned* __restrict__ cnt,
    float* __restrict__ out)
{
    __shared__ float Wl[NCH2 * ND * 128]; // 20 KB
    __shared__ float ul[BN * NCH2 * DP];  // 2 KB
    __shared__ float Tl[CELLS];           // 10 KB
    __shared__ float Bpl[ND * NCH2];      // 160 B
    __shared__ unsigned tk;
    const int t = threadIdx.x, j = t & 15, b = t >> 4;
    const int n0 = blockIdx.x * NCH2;
    constexpr float RS8 = 0.35355339059327373f;     // 1/sqrt(8)

    for (int g = t; g < NCH2 * ND * 32; g += 256) { // 5 indep float4 loads
        const int ch = g >> 5, w = g & 31;
        const int nn = ch / ND, q = ch - nn * ND;
        reinterpret_cast<float4*>(Wl)[g] =
            *reinterpret_cast<const float4*>(
                W + ((size_t)q * NN + n0 + nn) * (DD * DP) + w * 4);
    }
    if (t < BN * NCH2 * 2) {
        const int bb = t >> 3, r = t & 7, nn = r >> 1, half = r & 1;
        reinterpret_cast<float4*>(ul)[t] =
            *reinterpret_cast<const float4*>(
                u + ((size_t)bb * NN + n0 + nn) * DP + half * 4);
    }
    if (t < ND)
        reinterpret_cast<float4*>(Bpl)[t] =
            *reinterpret_cast<const float4*>(Bp + t * NN + n0);
    // reduce Tp[24][2560] -> Tl (<=3 float4-cells/thread x 24 indep loads)
    for (int g = t; g < CELLS / 4; g += 256) {
        float4 a = make_float4(0.f, 0.f, 0.f, 0.f);
#pragma unroll
        for (int c = 0; c < NCHK; ++c) {
            const float4 v = reinterpret_cast<const float4*>(Tp)[c * (CELLS / 4) + g];
            a.x += v.x; a.y += v.y; a.z += v.z; a.w += v.w;
        }
        reinterpret_cast<float4*>(Tl)[g] = a;
    }
    __syncthreads();

    float Treg[ND];
#pragma unroll
    for (int q = 0; q < ND; ++q) Treg[q] = Tl[q * 256 + t];  // conflict-free
    float Sacc[ND];
#pragma unroll
    for (int q = 0; q < ND; ++q) Sacc[q] = 0.f;

#pragma unroll
    for (int nn = 0; nn < NCH2; ++nn) {
        const float4 u0 = reinterpret_cast<const float4*>(ul)[(b * NCH2 + nn) * 2];
        const float4 u1 = reinterpret_cast<const float4*>(ul)[(b * NCH2 + nn) * 2 + 1];
        float uh[ND], a[ND];
#pragma unroll
        for (int q = 0; q < ND; ++q) {
            const float4* wp =
                reinterpret_cast<const float4*>(Wl) + (nn * ND + q) * 32 + j * 2;
            const float4 w0 = wp[0], w1 = wp[1];
            const float s =
                  w0.x * u0.x + w0.y * u0.y + w0.z * u0.z + w0.w * u0.w
                + w1.x * u1.x + w1.y * u1.y + w1.z * u1.z + w1.w * u1.w;
            uh[q] = s;
            float v = Treg[q] * s;                  // butterfly over 16 j-lanes
            v += __shfl_xor(v, 8, 16);
            v += __shfl_xor(v, 4, 16);
            v += __shfl_xor(v, 2, 16);
            v += __shfl_xor(v, 1, 16);
            a[q] = v * RS8;
        }
        float m = a[0];
#pragma unroll
        for (int q = 1; q < ND; ++q) m = fmaxf(m, a[q]);
        float e[ND], se = 0.f;
#pragma unroll
        for (int q = 0; q < ND; ++q) { e[q] = expf(a[q] - m); se += e[q]; }
        const float inv_se = 1.f / se;
#pragma unroll
        for (int q = 0; q < ND; ++q)
            Sacc[q] += (Bpl[q * NCH2 + nn] + e[q] * inv_se) * uh[q];
    }

    // S accumulation: ONLY write-through atomics (nothing dirty -> fence cheap)
    float* Sdst = Ssp + (size_t)(blockIdx.x & (SPLIT - 1)) * CELLS;
#pragma unroll
    for (int q = 0; q < ND; ++q)
        atomicAdd(&Sdst[q * 256 + t], Sacc[q]);

    // r12-proven last-arrival ticket (no spin, no wait)
    __syncthreads();                      // all block atomics drained
    __threadfence();                      // release
    if (t == 0) tk = __hip_atomic_fetch_add(cnt, 1u, __ATOMIC_ACQ_REL,
                                            __HIP_MEMORY_SCOPE_AGENT);
    __syncthreads();
    if (tk == NBLK2 - 1) {                // last block: squash + out
        __threadfence();                  // acquire
#pragma unroll
        for (int d = 0; d < ND; ++d) {
            float Sv = 0.f;
#pragma unroll
            for (int p = 0; p < SPLIT; ++p)   // EA-side atomic reads
                Sv += atomicAdd(&Ssp[(size_t)p * CELLS + d * 256 + t], 0.f);
            float n2 = Sv * Sv;               // t = b*16+j, 16-aligned groups
#pragma unroll
            for (int off = 8; off >= 1; off >>= 1)
                n2 += __shfl_xor(n2, off, 16);
            const float nrm = sqrtf(n2);
            const float coef = 1.f - 1.f / (expf(nrm) + 1e-7f);
            out[((size_t)b * ND + d) * DD + j] = Sv * (coef / (nrm + 1e-7f));
        }
    }
}

extern "C" void kernel_launch(void* const* d_in, const int* in_sizes, int n_in,
                              void* d_out, int out_size, void* d_ws, size_t ws_size,
                              hipStream_t stream) {
    const float* u  = nullptr;   // 147456
    const float* W  = nullptr;   // 1474560
    const float* Bp = nullptr;   // 11520
    for (int i = 0; i < n_in; ++i) {
        const int s = in_sizes[i];
        if (s == BN * NN * DP)            u  = (const float*)d_in[i];
        else if (s == ND * NN * DD * DP)  W  = (const float*)d_in[i];
        else if (s == ND * NN)            Bp = (const float*)d_in[i];
    }
    float* out = (float*)d_out;
    float* Tp  = (float*)d_ws;                    // 24*2560 fp32 = 245 KB
    float* Ssp = Tp + (size_t)NCHK * CELLS;       // 4*2560 fp32 = 40 KB
    unsigned* cnt = (unsigned*)(Ssp + (size_t)SPLIT * CELLS);
    // Tp fully written by K1; Ssp+cnt zeroed by K1 block 0 -> poison harmless

    caps_T<<<dim3(NBLK1), 256, 0, stream>>>(u, W, Tp, Ssp, cnt);
    caps_S<<<dim3(NBLK2), 256, 0, stream>>>(u, W, Bp, Tp, Ssp, cnt, out);
}

// Round 18
// 86.990 us; speedup vs baseline: 1.2087x; 1.2087x over previous
//
#include <hip/hip_runtime.h>
#include <hip/hip_bf16.h>

// DigitCaps, fp32 in / fp32 out:
//   u [16,1152,8], W [10,1152,16,8], Bp [10,1,1152], out [16,10,16]
// Exact algebra: A_sum[b,d,m] = dot(T[b,d,:], U_hat[b,d,m,:])/sqrt8,
//   T = sum_n U_hat;  C = softmax_d;  S = sum_n (Bp+C)*U_hat;  squash(S).
// Measured sync price list (MI355X, this harness):
//   spin barrier ~90us (r14); fence after dirty stores ~150us (r15);
//   ticket+fence ~30-40us/kernel (r12/r17); dispatch boundary ~10-20us
//   (r10/13/16 all = 83-85us at 4 dispatches regardless of internals).
// => kernel boundaries are the cheapest publisher. Round 18: THREE
// dispatches (minimum for the 2 true dependencies), zero in-kernel sync:
//   K1: Tp[16][2560] partials (plain stores).
//   K2: per-block redundant Tp-reduce (L2-hot 164KB) + softmax + Sp partials.
//   K3: Sp reduce + fused squash.
constexpr int BN = 16, NN = 1152, DP = 8, ND = 10, DD = 16;
constexpr int CELLS = BN * ND * DD;   // 2560; cell = d*256 + b*16 + j
constexpr int NCH1 = 72;              // n's per K1 block
constexpr int NCHK = NN / NCH1;       // 16 Tp chunks
constexpr int NBLK1 = NCHK * ND;      // 160 K1 blocks (one d each)
constexpr int NCH2 = 4;               // n's per K2 block
constexpr int NBLK2 = NN / NCH2;      // 288 K2 blocks
constexpr int RL = 16;                // K3 reduction lanes per cell

// ---- K1: partial T per (d, 72-n chunk); LDS-staged, plain stores ----
__global__ __launch_bounds__(256) void caps_T(
    const float* __restrict__ u, const float* __restrict__ W,
    float* __restrict__ Tp)
{
    __shared__ float Wl[NCH1 * 128];      // 36 KB: W[d, n0..n0+71, :, :]
    __shared__ float ul[BN * NCH1 * DP];  // 36 KB: u[:, n0..n0+71, :]
    const int t = threadIdx.x;
    const int d = blockIdx.x / NCHK, c = blockIdx.x % NCHK;
    const int n0 = c * NCH1;

    for (int g = t; g < NCH1 * 32; g += 256) {      // 9 indep float4 loads
        const int nn = g >> 5, w = g & 31;
        reinterpret_cast<float4*>(Wl)[g] =
            *reinterpret_cast<const float4*>(
                W + ((size_t)d * NN + n0 + nn) * (DD * DP) + w * 4);
    }
    for (int g = t; g < BN * NCH1 * 2; g += 256) {  // 9 indep float4 loads
        const int b = g / (NCH1 * 2), r = g % (NCH1 * 2);
        const int nn = r >> 1, half = r & 1;
        reinterpret_cast<float4*>(ul)[g] =
            *reinterpret_cast<const float4*>(
                u + ((size_t)b * NN + n0 + nn) * DP + half * 4);
    }
    __syncthreads();

    const int j = t & 15, b = t >> 4;
    float acc = 0.f;
#pragma unroll
    for (int nn = 0; nn < NCH1; ++nn) {   // u: broadcast; W: 4-way (1.58x ok)
        const float4 u0 = reinterpret_cast<const float4*>(ul)[(b * NCH1 + nn) * 2];
        const float4 u1 = reinterpret_cast<const float4*>(ul)[(b * NCH1 + nn) * 2 + 1];
        const float4* wp = reinterpret_cast<const float4*>(Wl) + nn * 32 + j * 2;
        const float4 w0 = wp[0], w1 = wp[1];
        acc += w0.x * u0.x + w0.y * u0.y + w0.z * u0.z + w0.w * u0.w
             + w1.x * u1.x + w1.y * u1.y + w1.z * u1.z + w1.w * u1.w;
    }
    Tp[(size_t)c * CELLS + d * 256 + t] = acc;      // 1 KB coalesced run
}

// ---- K2: redundant Tp-reduce -> softmax_d -> Sp partials (plain) ----
__global__ __launch_bounds__(256) void caps_S(
    const float* __restrict__ u, const float* __restrict__ W,
    const float* __restrict__ Bp, const float* __restrict__ Tp,
    float* __restrict__ Sp)
{
    __shared__ float Wl[NCH2 * ND * 128]; // 20 KB
    __shared__ float ul[BN * NCH2 * DP];  // 2 KB
    __shared__ float Tl[CELLS];           // 10 KB
    __shared__ float Bpl[ND * NCH2];      // 160 B
    const int t = threadIdx.x, j = t & 15, b = t >> 4;
    const int n0 = blockIdx.x * NCH2;
    constexpr float RS8 = 0.35355339059327373f;     // 1/sqrt(8)

    for (int g = t; g < NCH2 * ND * 32; g += 256) { // 5 indep float4 loads
        const int ch = g >> 5, w = g & 31;
        const int nn = ch / ND, q = ch - nn * ND;
        reinterpret_cast<float4*>(Wl)[g] =
            *reinterpret_cast<const float4*>(
                W + ((size_t)q * NN + n0 + nn) * (DD * DP) + w * 4);
    }
    if (t < BN * NCH2 * 2) {
        const int bb = t >> 3, r = t & 7, nn = r >> 1, half = r & 1;
        reinterpret_cast<float4*>(ul)[t] =
            *reinterpret_cast<const float4*>(
                u + ((size_t)bb * NN + n0 + nn) * DP + half * 4);
    }
    if (t < ND)
        reinterpret_cast<float4*>(Bpl)[t] =
            *reinterpret_cast<const float4*>(Bp + t * NN + n0);
    // reduce Tp[16][2560] -> Tl: 2.5 float4-cells/thread x 16 indep loads
    for (int g = t; g < CELLS / 4; g += 256) {
        float4 a = make_float4(0.f, 0.f, 0.f, 0.f);
#pragma unroll
        for (int c = 0; c < NCHK; ++c) {
            const float4 v =
                reinterpret_cast<const float4*>(Tp)[c * (CELLS / 4) + g];
            a.x += v.x; a.y += v.y; a.z += v.z; a.w += v.w;
        }
        reinterpret_cast<float4*>(Tl)[g] = a;
    }
    __syncthreads();

    float Treg[ND];
#pragma unroll
    for (int q = 0; q < ND; ++q) Treg[q] = Tl[q * 256 + t];  // conflict-free
    float Sacc[ND];
#pragma unroll
    for (int q = 0; q < ND; ++q) Sacc[q] = 0.f;

#pragma unroll
    for (int nn = 0; nn < NCH2; ++nn) {
        const float4 u0 = reinterpret_cast<const float4*>(ul)[(b * NCH2 + nn) * 2];
        const float4 u1 = reinterpret_cast<const float4*>(ul)[(b * NCH2 + nn) * 2 + 1];
        float uh[ND], a[ND];
#pragma unroll
        for (int q = 0; q < ND; ++q) {
            const float4* wp =
                reinterpret_cast<const float4*>(Wl) + (nn * ND + q) * 32 + j * 2;
            const float4 w0 = wp[0], w1 = wp[1];
            const float s =
                  w0.x * u0.x + w0.y * u0.y + w0.z * u0.z + w0.w * u0.w
                + w1.x * u1.x + w1.y * u1.y + w1.z * u1.z + w1.w * u1.w;
            uh[q] = s;
            float v = Treg[q] * s;                  // butterfly over 16 j-lanes
            v += __shfl_xor(v, 8, 16);
            v += __shfl_xor(v, 4, 16);
            v += __shfl_xor(v, 2, 16);
            v += __shfl_xor(v, 1, 16);
            a[q] = v * RS8;
        }
        float m = a[0];
#pragma unroll
        for (int q = 1; q < ND; ++q) m = fmaxf(m, a[q]);
        float e[ND], se = 0.f;
#pragma unroll
        for (int q = 0; q < ND; ++q) { e[q] = expf(a[q] - m); se += e[q]; }
        const float inv_se = 1.f / se;
#pragma unroll
        for (int q = 0; q < ND; ++q)
            Sacc[q] += (Bpl[q * NCH2 + nn] + e[q] * inv_se) * uh[q];
    }
    float* dst = Sp + (size_t)blockIdx.x * CELLS;
#pragma unroll
    for (int q = 0; q < ND; ++q) dst[q * 256 + t] = Sacc[q];  // plain stores
}

// ---- K3: reduce Sp[288][2560] + fused squash; 160 blocks = (q,b) ----
__global__ __launch_bounds__(256) void reduce_S_out(
    const float* __restrict__ Sp, float* __restrict__ out)
{
    __shared__ float red[256];
    const int q = blockIdx.x >> 4, b = blockIdx.x & 15;
    const int t = threadIdx.x, j = t & 15, cc = t >> 4;
    const int cell = q * 256 + b * 16 + j;
    float s0 = 0.f, s1 = 0.f;
#pragma unroll
    for (int k = 0; k < NBLK2 / RL; k += 2) {       // 18 independent loads
        s0 += Sp[(size_t)(cc + RL * (k + 0)) * CELLS + cell];
        s1 += Sp[(size_t)(cc + RL * (k + 1)) * CELLS + cell];
    }
    red[t] = s0 + s1;
    __syncthreads();
    if (t < RL) {                                   // t = j
        float Sv = 0.f;
#pragma unroll
        for (int g = 0; g < RL; ++g) Sv += red[t + RL * g];
        float n2 = Sv * Sv;
#pragma unroll
        for (int off = 8; off >= 1; off >>= 1) n2 += __shfl_xor(n2, off, 16);
        const float nrm = sqrtf(n2);
        const float coef = 1.f - 1.f / (expf(nrm) + 1e-7f);
        out[((size_t)b * ND + q) * DD + t] = Sv * (coef / (nrm + 1e-7f));
    }
}

extern "C" void kernel_launch(void* const* d_in, const int* in_sizes, int n_in,
                              void* d_out, int out_size, void* d_ws, size_t ws_size,
                              hipStream_t stream) {
    const float* u  = nullptr;   // 147456
    const float* W  = nullptr;   // 1474560
    const float* Bp = nullptr;   // 11520
    for (int i = 0; i < n_in; ++i) {
        const int s = in_sizes[i];
        if (s == BN * NN * DP)            u  = (const float*)d_in[i];
        else if (s == ND * NN * DD * DP)  W  = (const float*)d_in[i];
        else if (s == ND * NN)            Bp = (const float*)d_in[i];
    }
    float* out = (float*)d_out;
    float* Tp = (float*)d_ws;                     // 16*2560 fp32 = 164 KB
    float* Sp = Tp + (size_t)NCHK * CELLS;        // 288*2560 fp32 = 2.95 MB
    // every ws word written before read -> poison harmless; no memset

    caps_T      <<<dim3(NBLK1), 256, 0, stream>>>(u, W, Tp);
    caps_S      <<<dim3(NBLK2), 256, 0, stream>>>(u, W, Bp, Tp, Sp);
    reduce_S_out<<<dim3(ND * BN), 256, 0, stream>>>(Sp, out);
}